// Round 2
// baseline (287.376 us; speedup 1.0000x reference)
//
#include <hip/hip_runtime.h>
#include <hip/hip_bf16.h>
#include <math.h>

#define T_TOKENS 8192
#define N_EXP    64
#define CAP      320   // floor(2 * 1.25 * 8192 / 64) = 320, even, > MIN_CAPACITY
#define ROW4     (N_EXP * CAP / 4)   // float4 chunks per (expert,cap) row = 5120

// ---------------------------------------------------------------------------
// Kernel 1: per-token softmax + top-2. One 64-lane wave per token.
// ---------------------------------------------------------------------------
__global__ __launch_bounds__(256) void moe_topk_kernel(
    const float* __restrict__ in,
    int* __restrict__ top1, int* __restrict__ top2,
    float* __restrict__ w1, float* __restrict__ w2)
{
    const int token = blockIdx.x * 4 + (threadIdx.x >> 6);
    const int lane  = threadIdx.x & 63;
    if (token >= T_TOKENS) return;

    const float x = in[(size_t)token * N_EXP + lane];

    // argmax with first-index tiebreak (matches jnp.argmax)
    float v = x; int idx = lane;
    #pragma unroll
    for (int off = 32; off; off >>= 1) {
        float vo = __shfl_xor(v, off);
        int   io = __shfl_xor(idx, off);
        if (vo > v || (vo == v && io < idx)) { v = vo; idx = io; }
    }
    const float m  = v;
    const int   i1 = idx;

    // softmax denominator
    float s = expf(x - m);
    #pragma unroll
    for (int off = 32; off; off >>= 1) s += __shfl_xor(s, off);

    // second argmax (exclude i1)
    float v2 = (lane == i1) ? -INFINITY : x;
    int idx2 = lane;
    #pragma unroll
    for (int off = 32; off; off >>= 1) {
        float vo = __shfl_xor(v2, off);
        int   io = __shfl_xor(idx2, off);
        if (vo > v2 || (vo == v2 && io < idx2)) { v2 = vo; idx2 = io; }
    }

    if (lane == 0) {
        top1[token] = i1;
        top2[token] = idx2;
        w1[token]   = 1.0f / s;
        w2[token]   = expf(v2 - m) / s;
    }
}

// ---------------------------------------------------------------------------
// Kernel 2: one block per expert. Ballot-scan cumsum ranks; emit packed slot
// index c = e*CAP + r (or -1 if dropped) per token, plus used_capacity.
// Each token is written exactly once per pass (by its routed expert's block).
// ---------------------------------------------------------------------------
__global__ __launch_bounds__(256) void moe_rank_kernel(
    const int* __restrict__ top1, const int* __restrict__ top2,
    int* __restrict__ c1, int* __restrict__ c2,
    float* __restrict__ used)
{
    const int e    = blockIdx.x;
    const int tid  = threadIdx.x;
    const int lane = tid & 63;
    const int wid  = tid >> 6;

    __shared__ int wsum[4];

    const unsigned long long below_mask = (lane == 63)
        ? 0x7FFFFFFFFFFFFFFFull
        : ((1ull << lane) - 1ull);

    // pass 1: top1 ranks
    int base = 0;
    for (int t0 = 0; t0 < T_TOKENS; t0 += 256) {
        const int  t     = t0 + tid;
        const bool match = (top1[t] == e);
        const unsigned long long mb = __ballot(match);
        const int below = __popcll(mb & below_mask);
        if (lane == 0) wsum[wid] = __popcll(mb);
        __syncthreads();
        int pre = 0;
        for (int w = 0; w < wid; ++w) pre += wsum[w];
        const int tot = wsum[0] + wsum[1] + wsum[2] + wsum[3];
        if (match) {
            const int r = base + pre + below;
            c1[t] = (r < CAP) ? (e * CAP + r) : -1;
        }
        base += tot;
        __syncthreads();
    }
    const int count1 = base;

    // pass 2: top2 ranks, offset by total top1 count for this expert
    int base2 = 0;
    for (int t0 = 0; t0 < T_TOKENS; t0 += 256) {
        const int  t     = t0 + tid;
        const bool match = (top2[t] == e);
        const unsigned long long mb = __ballot(match);
        const int below = __popcll(mb & below_mask);
        if (lane == 0) wsum[wid] = __popcll(mb);
        __syncthreads();
        int pre = 0;
        for (int w = 0; w < wid; ++w) pre += wsum[w];
        const int tot = wsum[0] + wsum[1] + wsum[2] + wsum[3];
        if (match) {
            const int r = count1 + base2 + pre + below;
            c2[t] = (r < CAP) ? (e * CAP + r) : -1;
        }
        base2 += tot;
        __syncthreads();
    }
    const int count2 = base2;

    if (tid == 0) {
        const int kept1 = min(count1, CAP);
        const int kept2 = min(max(CAP - count1, 0), count2);
        used[e] = (float)(kept1 + kept2);
    }
}

// ---------------------------------------------------------------------------
// Kernel 3: one block per token row. Stream cb_weight + sec_mask rows as
// coalesced float4 stores, inserting the <=2 nonzeros inline. Every output
// element is written exactly once; no separate fill pass.
// ---------------------------------------------------------------------------
__global__ __launch_bounds__(256) void moe_row_write_kernel(
    const int* __restrict__ c1, const int* __restrict__ c2,
    const float* __restrict__ w1, const float* __restrict__ w2,
    float* __restrict__ out)
{
    const int t   = blockIdx.x;
    const int tid = threadIdx.x;

    const int   p1 = c1[t];          // packed slot (e*CAP+r) or -1
    const int   p2 = c2[t];
    const float a  = w1[t];
    const float b  = w2[t];
    const int   q1 = p1 >> 2;        // chunk containing p1 (negative if dropped)
    const int   q2 = p2 >> 2;

    float4* __restrict__ cb  = (float4*)(out + N_EXP) + (size_t)t * ROW4;
    float4* __restrict__ sec = cb + (size_t)T_TOKENS * ROW4;

    #pragma unroll
    for (int i = 0; i < ROW4 / 256; ++i) {      // 20 iterations
        const int idx  = i * 256 + tid;
        const int base = idx * 4;
        float4 v = make_float4(0.f, 0.f, 0.f, 0.f);
        float4 s = make_float4(0.f, 0.f, 0.f, 0.f);
        if (idx == q1 || idx == q2) {           // rare: <=2 lanes per row
            float* vp = (float*)&v;
            float* sp = (float*)&s;
            #pragma unroll
            for (int j = 0; j < 4; ++j) {       // static index -> registers
                const int pos = base + j;
                float vv = 0.f, ss = 0.f;
                if (pos == p1) { vv += a; ss = 1.f; }
                if (pos == p2) { vv += b; ss = 1.f; }
                vp[j] = vv; sp[j] = ss;
            }
        }
        cb[idx]  = v;
        sec[idx] = s;
    }
}

// ---------------------------------------------------------------------------
extern "C" void kernel_launch(void* const* d_in, const int* in_sizes, int n_in,
                              void* d_out, int out_size, void* d_ws, size_t ws_size,
                              hipStream_t stream) {
    const float* in  = (const float*)d_in[0];
    float*       out = (float*)d_out;

    // workspace: top1 | top2 | c1 | c2 (int[T] each) | w1 | w2 (float[T])
    int*   top1 = (int*)d_ws;
    int*   top2 = top1 + T_TOKENS;
    int*   c1   = top2 + T_TOKENS;
    int*   c2   = c1 + T_TOKENS;
    float* w1   = (float*)(c2 + T_TOKENS);
    float* w2   = w1 + T_TOKENS;

    moe_topk_kernel<<<T_TOKENS / 4, 256, 0, stream>>>(in, top1, top2, w1, w2);
    moe_rank_kernel<<<N_EXP, 256, 0, stream>>>(top1, top2, c1, c2, out);
    moe_row_write_kernel<<<T_TOKENS, 256, 0, stream>>>(c1, c2, w1, w2, out + 0);
}

// Round 4
// 270.096 us; speedup vs baseline: 1.0640x; 1.0640x over previous
//
#include <hip/hip_runtime.h>
#include <hip/hip_bf16.h>
#include <math.h>

#define T_TOKENS 8192
#define N_EXP    64
#define CAP      320   // floor(2 * 1.25 * 8192 / 64) = 320, even, > MIN_CAPACITY
#define ROW4     (N_EXP * CAP / 4)   // float4 chunks per (expert,cap) row = 5120

typedef float f32x4 __attribute__((ext_vector_type(4)));

// ---------------------------------------------------------------------------
// Kernel 1: per-token softmax + top-2. One 64-lane wave per token.
// ---------------------------------------------------------------------------
__global__ __launch_bounds__(256) void moe_topk_kernel(
    const float* __restrict__ in,
    int* __restrict__ top1, int* __restrict__ top2,
    float* __restrict__ w1, float* __restrict__ w2)
{
    const int token = blockIdx.x * 4 + (threadIdx.x >> 6);
    const int lane  = threadIdx.x & 63;
    if (token >= T_TOKENS) return;

    const float x = in[(size_t)token * N_EXP + lane];

    // argmax with first-index tiebreak (matches jnp.argmax)
    float v = x; int idx = lane;
    #pragma unroll
    for (int off = 32; off; off >>= 1) {
        float vo = __shfl_xor(v, off);
        int   io = __shfl_xor(idx, off);
        if (vo > v || (vo == v && io < idx)) { v = vo; idx = io; }
    }
    const float m  = v;
    const int   i1 = idx;

    // softmax denominator
    float s = expf(x - m);
    #pragma unroll
    for (int off = 32; off; off >>= 1) s += __shfl_xor(s, off);

    // second argmax (exclude i1)
    float v2 = (lane == i1) ? -INFINITY : x;
    int idx2 = lane;
    #pragma unroll
    for (int off = 32; off; off >>= 1) {
        float vo = __shfl_xor(v2, off);
        int   io = __shfl_xor(idx2, off);
        if (vo > v2 || (vo == v2 && io < idx2)) { v2 = vo; idx2 = io; }
    }

    if (lane == 0) {
        top1[token] = i1;
        top2[token] = idx2;
        w1[token]   = 1.0f / s;
        w2[token]   = expf(v2 - m) / s;
    }
}

// ---------------------------------------------------------------------------
// Kernel 2: one 1024-thread block per expert. Two-level parallel scan:
// each thread owns 8 consecutive tokens, wave shfl_up scan + 16-wave LDS
// scan gives the exclusive prefix; ranks assigned serially within the
// thread's 8 tokens. Emits packed slot c = e*CAP + r (or -1 if dropped).
// ---------------------------------------------------------------------------
__global__ __launch_bounds__(1024) void moe_rank_kernel(
    const int* __restrict__ top1, const int* __restrict__ top2,
    int* __restrict__ c1, int* __restrict__ c2,
    float* __restrict__ used)
{
    const int e    = blockIdx.x;
    const int tid  = threadIdx.x;
    const int lane = tid & 63;
    const int wid  = tid >> 6;           // 16 waves

    __shared__ int wsA[16], wsB[16];

    // ---------------- pass 1: top1 ----------------
    const int4 a1 = ((const int4*)top1)[tid * 2];
    const int4 b1 = ((const int4*)top1)[tid * 2 + 1];
    const int m0 = (a1.x == e), m1 = (a1.y == e), m2 = (a1.z == e), m3 = (a1.w == e);
    const int m4 = (b1.x == e), m5 = (b1.y == e), m6 = (b1.z == e), m7 = (b1.w == e);
    const int cnt1 = m0 + m1 + m2 + m3 + m4 + m5 + m6 + m7;

    int sc = cnt1;
    #pragma unroll
    for (int off = 1; off < 64; off <<= 1) {
        int n = __shfl_up(sc, off);
        if (lane >= off) sc += n;
    }
    if (lane == 63) wsA[wid] = sc;
    __syncthreads();
    int wbase = 0, total1 = 0;
    #pragma unroll
    for (int w = 0; w < 16; ++w) {
        const int sv = wsA[w];
        if (w < wid) wbase += sv;
        total1 += sv;
    }
    {
        int r = wbase + sc - cnt1;       // exclusive prefix for this segment
        const int t0 = tid * 8;
        if (m0) { c1[t0 + 0] = (r < CAP) ? (e * CAP + r) : -1; ++r; }
        if (m1) { c1[t0 + 1] = (r < CAP) ? (e * CAP + r) : -1; ++r; }
        if (m2) { c1[t0 + 2] = (r < CAP) ? (e * CAP + r) : -1; ++r; }
        if (m3) { c1[t0 + 3] = (r < CAP) ? (e * CAP + r) : -1; ++r; }
        if (m4) { c1[t0 + 4] = (r < CAP) ? (e * CAP + r) : -1; ++r; }
        if (m5) { c1[t0 + 5] = (r < CAP) ? (e * CAP + r) : -1; ++r; }
        if (m6) { c1[t0 + 6] = (r < CAP) ? (e * CAP + r) : -1; ++r; }
        if (m7) { c1[t0 + 7] = (r < CAP) ? (e * CAP + r) : -1; ++r; }
    }

    // ---------------- pass 2: top2 (offset by total1) ----------------
    const int4 a2 = ((const int4*)top2)[tid * 2];
    const int4 b2 = ((const int4*)top2)[tid * 2 + 1];
    const int n0 = (a2.x == e), n1 = (a2.y == e), n2 = (a2.z == e), n3 = (a2.w == e);
    const int n4 = (b2.x == e), n5 = (b2.y == e), n6 = (b2.z == e), n7 = (b2.w == e);
    const int cnt2 = n0 + n1 + n2 + n3 + n4 + n5 + n6 + n7;

    int sc2 = cnt2;
    #pragma unroll
    for (int off = 1; off < 64; off <<= 1) {
        int n = __shfl_up(sc2, off);
        if (lane >= off) sc2 += n;
    }
    if (lane == 63) wsB[wid] = sc2;
    __syncthreads();
    int wbase2 = 0, total2 = 0;
    #pragma unroll
    for (int w = 0; w < 16; ++w) {
        const int sv = wsB[w];
        if (w < wid) wbase2 += sv;
        total2 += sv;
    }
    {
        int r = total1 + wbase2 + sc2 - cnt2;
        const int t0 = tid * 8;
        if (n0) { c2[t0 + 0] = (r < CAP) ? (e * CAP + r) : -1; ++r; }
        if (n1) { c2[t0 + 1] = (r < CAP) ? (e * CAP + r) : -1; ++r; }
        if (n2) { c2[t0 + 2] = (r < CAP) ? (e * CAP + r) : -1; ++r; }
        if (n3) { c2[t0 + 3] = (r < CAP) ? (e * CAP + r) : -1; ++r; }
        if (n4) { c2[t0 + 4] = (r < CAP) ? (e * CAP + r) : -1; ++r; }
        if (n5) { c2[t0 + 5] = (r < CAP) ? (e * CAP + r) : -1; ++r; }
        if (n6) { c2[t0 + 6] = (r < CAP) ? (e * CAP + r) : -1; ++r; }
        if (n7) { c2[t0 + 7] = (r < CAP) ? (e * CAP + r) : -1; ++r; }
    }

    if (tid == 0) {
        const int kept1 = min(total1, CAP);
        const int kept2 = min(max(CAP - total1, 0), total2);
        used[e] = (float)(kept1 + kept2);
    }
}

// ---------------------------------------------------------------------------
// Kernel 3: one block per token row. Stream cb_weight + sec_mask rows as
// coalesced nontemporal float4 stores, inserting the <=2 nonzeros inline.
// ---------------------------------------------------------------------------
__global__ __launch_bounds__(256) void moe_row_write_kernel(
    const int* __restrict__ c1, const int* __restrict__ c2,
    const float* __restrict__ w1, const float* __restrict__ w2,
    float* __restrict__ out)
{
    const int t   = blockIdx.x;
    const int tid = threadIdx.x;

    const int   p1 = c1[t];          // packed slot (e*CAP+r) or -1
    const int   p2 = c2[t];
    const float a  = w1[t];
    const float b  = w2[t];
    const int   q1 = p1 >> 2;        // chunk containing p1 (negative if dropped)
    const int   q2 = p2 >> 2;

    f32x4* __restrict__ cb  = (f32x4*)(out + N_EXP) + (size_t)t * ROW4;
    f32x4* __restrict__ sec = cb + (size_t)T_TOKENS * ROW4;

    #pragma unroll
    for (int i = 0; i < ROW4 / 256; ++i) {      // 20 iterations
        const int idx = i * 256 + tid;
        f32x4 v = {0.f, 0.f, 0.f, 0.f};
        f32x4 s = {0.f, 0.f, 0.f, 0.f};
        if (idx == q1 || idx == q2) {           // wave-uniform-rare branch
            const int base = idx * 4;
            #pragma unroll
            for (int j = 0; j < 4; ++j) {       // static index -> registers
                const int pos = base + j;
                float vv = 0.f, ss = 0.f;
                if (pos == p1) { vv += a; ss = 1.f; }
                if (pos == p2) { vv += b; ss = 1.f; }
                v[j] = vv; s[j] = ss;
            }
        }
        __builtin_nontemporal_store(v, cb + idx);
        __builtin_nontemporal_store(s, sec + idx);
    }
}

// ---------------------------------------------------------------------------
extern "C" void kernel_launch(void* const* d_in, const int* in_sizes, int n_in,
                              void* d_out, int out_size, void* d_ws, size_t ws_size,
                              hipStream_t stream) {
    const float* in  = (const float*)d_in[0];
    float*       out = (float*)d_out;

    // workspace: top1 | top2 | c1 | c2 (int[T] each) | w1 | w2 (float[T])
    int*   top1 = (int*)d_ws;
    int*   top2 = top1 + T_TOKENS;
    int*   c1   = top2 + T_TOKENS;
    int*   c2   = c1 + T_TOKENS;
    float* w1   = (float*)(c2 + T_TOKENS);
    float* w2   = w1 + T_TOKENS;

    moe_topk_kernel<<<T_TOKENS / 4, 256, 0, stream>>>(in, top1, top2, w1, w2);
    moe_rank_kernel<<<N_EXP, 1024, 0, stream>>>(top1, top2, c1, c2, out);
    moe_row_write_kernel<<<T_TOKENS, 256, 0, stream>>>(c1, c2, w1, w2, out);
}

// Round 5
// 259.603 us; speedup vs baseline: 1.1070x; 1.0404x over previous
//
#include <hip/hip_runtime.h>
#include <hip/hip_bf16.h>
#include <math.h>

#define T_TOKENS 8192
#define N_EXP    64
#define CAP      320   // floor(2 * 1.25 * 8192 / 64) = 320, even, > MIN_CAPACITY
#define ROW4     (N_EXP * CAP / 4)   // float4 chunks per (expert,cap) row = 5120

typedef float f32x4 __attribute__((ext_vector_type(4)));

// ---------------------------------------------------------------------------
// Kernel 1: per-token softmax + top-2. One 64-lane wave per token.
// ---------------------------------------------------------------------------
__global__ __launch_bounds__(256) void moe_topk_kernel(
    const float* __restrict__ in,
    int* __restrict__ top1, int* __restrict__ top2,
    float* __restrict__ w1, float* __restrict__ w2)
{
    const int token = blockIdx.x * 4 + (threadIdx.x >> 6);
    const int lane  = threadIdx.x & 63;
    if (token >= T_TOKENS) return;

    const float x = in[(size_t)token * N_EXP + lane];

    // argmax with first-index tiebreak (matches jnp.argmax)
    float v = x; int idx = lane;
    #pragma unroll
    for (int off = 32; off; off >>= 1) {
        float vo = __shfl_xor(v, off);
        int   io = __shfl_xor(idx, off);
        if (vo > v || (vo == v && io < idx)) { v = vo; idx = io; }
    }
    const float m  = v;
    const int   i1 = idx;

    // softmax denominator
    float s = expf(x - m);
    #pragma unroll
    for (int off = 32; off; off >>= 1) s += __shfl_xor(s, off);

    // second argmax (exclude i1)
    float v2 = (lane == i1) ? -INFINITY : x;
    int idx2 = lane;
    #pragma unroll
    for (int off = 32; off; off >>= 1) {
        float vo = __shfl_xor(v2, off);
        int   io = __shfl_xor(idx2, off);
        if (vo > v2 || (vo == v2 && io < idx2)) { v2 = vo; idx2 = io; }
    }

    if (lane == 0) {
        top1[token] = i1;
        top2[token] = idx2;
        w1[token]   = 1.0f / s;
        w2[token]   = expf(v2 - m) / s;
    }
}

// ---------------------------------------------------------------------------
// Kernel 2: one 1024-thread block per expert. Two-level parallel scan:
// each thread owns 8 consecutive tokens, wave shfl_up scan + 16-wave LDS
// scan gives the exclusive prefix; ranks assigned serially within the
// thread's 8 tokens. Emits packed slot c = e*CAP + r (or -1 if dropped).
// ---------------------------------------------------------------------------
__global__ __launch_bounds__(1024) void moe_rank_kernel(
    const int* __restrict__ top1, const int* __restrict__ top2,
    int* __restrict__ c1, int* __restrict__ c2,
    float* __restrict__ used)
{
    const int e    = blockIdx.x;
    const int tid  = threadIdx.x;
    const int lane = tid & 63;
    const int wid  = tid >> 6;           // 16 waves

    __shared__ int wsA[16], wsB[16];

    // ---------------- pass 1: top1 ----------------
    const int4 a1 = ((const int4*)top1)[tid * 2];
    const int4 b1 = ((const int4*)top1)[tid * 2 + 1];
    const int m0 = (a1.x == e), m1 = (a1.y == e), m2 = (a1.z == e), m3 = (a1.w == e);
    const int m4 = (b1.x == e), m5 = (b1.y == e), m6 = (b1.z == e), m7 = (b1.w == e);
    const int cnt1 = m0 + m1 + m2 + m3 + m4 + m5 + m6 + m7;

    int sc = cnt1;
    #pragma unroll
    for (int off = 1; off < 64; off <<= 1) {
        int n = __shfl_up(sc, off);
        if (lane >= off) sc += n;
    }
    if (lane == 63) wsA[wid] = sc;
    __syncthreads();
    int wbase = 0, total1 = 0;
    #pragma unroll
    for (int w = 0; w < 16; ++w) {
        const int sv = wsA[w];
        if (w < wid) wbase += sv;
        total1 += sv;
    }
    {
        int r = wbase + sc - cnt1;       // exclusive prefix for this segment
        const int t0 = tid * 8;
        if (m0) { c1[t0 + 0] = (r < CAP) ? (e * CAP + r) : -1; ++r; }
        if (m1) { c1[t0 + 1] = (r < CAP) ? (e * CAP + r) : -1; ++r; }
        if (m2) { c1[t0 + 2] = (r < CAP) ? (e * CAP + r) : -1; ++r; }
        if (m3) { c1[t0 + 3] = (r < CAP) ? (e * CAP + r) : -1; ++r; }
        if (m4) { c1[t0 + 4] = (r < CAP) ? (e * CAP + r) : -1; ++r; }
        if (m5) { c1[t0 + 5] = (r < CAP) ? (e * CAP + r) : -1; ++r; }
        if (m6) { c1[t0 + 6] = (r < CAP) ? (e * CAP + r) : -1; ++r; }
        if (m7) { c1[t0 + 7] = (r < CAP) ? (e * CAP + r) : -1; ++r; }
    }

    // ---------------- pass 2: top2 (offset by total1) ----------------
    const int4 a2 = ((const int4*)top2)[tid * 2];
    const int4 b2 = ((const int4*)top2)[tid * 2 + 1];
    const int n0 = (a2.x == e), n1 = (a2.y == e), n2 = (a2.z == e), n3 = (a2.w == e);
    const int n4 = (b2.x == e), n5 = (b2.y == e), n6 = (b2.z == e), n7 = (b2.w == e);
    const int cnt2 = n0 + n1 + n2 + n3 + n4 + n5 + n6 + n7;

    int sc2 = cnt2;
    #pragma unroll
    for (int off = 1; off < 64; off <<= 1) {
        int n = __shfl_up(sc2, off);
        if (lane >= off) sc2 += n;
    }
    if (lane == 63) wsB[wid] = sc2;
    __syncthreads();
    int wbase2 = 0, total2 = 0;
    #pragma unroll
    for (int w = 0; w < 16; ++w) {
        const int sv = wsB[w];
        if (w < wid) wbase2 += sv;
        total2 += sv;
    }
    {
        int r = total1 + wbase2 + sc2 - cnt2;
        const int t0 = tid * 8;
        if (n0) { c2[t0 + 0] = (r < CAP) ? (e * CAP + r) : -1; ++r; }
        if (n1) { c2[t0 + 1] = (r < CAP) ? (e * CAP + r) : -1; ++r; }
        if (n2) { c2[t0 + 2] = (r < CAP) ? (e * CAP + r) : -1; ++r; }
        if (n3) { c2[t0 + 3] = (r < CAP) ? (e * CAP + r) : -1; ++r; }
        if (n4) { c2[t0 + 4] = (r < CAP) ? (e * CAP + r) : -1; ++r; }
        if (n5) { c2[t0 + 5] = (r < CAP) ? (e * CAP + r) : -1; ++r; }
        if (n6) { c2[t0 + 6] = (r < CAP) ? (e * CAP + r) : -1; ++r; }
        if (n7) { c2[t0 + 7] = (r < CAP) ? (e * CAP + r) : -1; ++r; }
    }

    if (tid == 0) {
        const int kept1 = min(total1, CAP);
        const int kept2 = min(max(CAP - total1, 0), total2);
        used[e] = (float)(kept1 + kept2);
    }
}

// ---------------------------------------------------------------------------
// Kernel 3: one block per output row, 16384 blocks. Block b < T writes the
// cb_weight row b; block b >= T writes the sec_mask row b-T. Each block
// streams ONE linear 80 KB region with plain coalesced float4 stores,
// inserting the <=2 nonzeros inline (w1/w2 for cb, 1.0 for sec).
// ---------------------------------------------------------------------------
__global__ __launch_bounds__(256) void moe_row_write_kernel(
    const int* __restrict__ c1, const int* __restrict__ c2,
    const float* __restrict__ w1, const float* __restrict__ w2,
    float* __restrict__ out)
{
    const int b   = blockIdx.x;
    const int tid = threadIdx.x;
    const bool is_sec = (b >= T_TOKENS);
    const int t   = is_sec ? (b - T_TOKENS) : b;

    const int   p1 = c1[t];          // packed slot (e*CAP+r) or -1
    const int   p2 = c2[t];
    const float a  = is_sec ? 1.0f : w1[t];
    const float c  = is_sec ? 1.0f : w2[t];
    const int   q1 = p1 >> 2;        // chunk containing p1 (negative if dropped)
    const int   q2 = p2 >> 2;

    f32x4* __restrict__ row = (f32x4*)(out + N_EXP) + (size_t)b * ROW4;

    #pragma unroll
    for (int i = 0; i < ROW4 / 256; ++i) {      // 20 iterations
        const int idx = i * 256 + tid;
        f32x4 v = {0.f, 0.f, 0.f, 0.f};
        if (idx == q1 || idx == q2) {           // wave-uniform-rare branch
            const int base = idx * 4;
            #pragma unroll
            for (int j = 0; j < 4; ++j) {       // static index -> registers
                const int pos = base + j;
                float vv = 0.f;
                if (pos == p1) vv += a;
                if (pos == p2) vv += c;
                v[j] = vv;
            }
        }
        row[idx] = v;
    }
}

// ---------------------------------------------------------------------------
extern "C" void kernel_launch(void* const* d_in, const int* in_sizes, int n_in,
                              void* d_out, int out_size, void* d_ws, size_t ws_size,
                              hipStream_t stream) {
    const float* in  = (const float*)d_in[0];
    float*       out = (float*)d_out;

    // workspace: top1 | top2 | c1 | c2 (int[T] each) | w1 | w2 (float[T])
    int*   top1 = (int*)d_ws;
    int*   top2 = top1 + T_TOKENS;
    int*   c1   = top2 + T_TOKENS;
    int*   c2   = c1 + T_TOKENS;
    float* w1   = (float*)(c2 + T_TOKENS);
    float* w2   = w1 + T_TOKENS;

    moe_topk_kernel<<<T_TOKENS / 4, 256, 0, stream>>>(in, top1, top2, w1, w2);
    moe_rank_kernel<<<N_EXP, 1024, 0, stream>>>(top1, top2, c1, c2, out);
    moe_row_write_kernel<<<2 * T_TOKENS, 256, 0, stream>>>(c1, c2, w1, w2, out);
}

// Round 6
// 232.390 us; speedup vs baseline: 1.2366x; 1.1171x over previous
//
#include <hip/hip_runtime.h>
#include <hip/hip_bf16.h>
#include <math.h>

#define T_TOKENS 8192
#define N_EXP    64
#define CAP      320   // floor(2 * 1.25 * 8192 / 64) = 320, even, > MIN_CAPACITY
#define ROWSZ    (N_EXP * CAP)       // 20480 floats per token row

// ---------------------------------------------------------------------------
// Kernel 1: per-token softmax + top-2. One 64-lane wave per token.
// ---------------------------------------------------------------------------
__global__ __launch_bounds__(256) void moe_topk_kernel(
    const float* __restrict__ in,
    int* __restrict__ top1, int* __restrict__ top2,
    float* __restrict__ w1, float* __restrict__ w2)
{
    const int token = blockIdx.x * 4 + (threadIdx.x >> 6);
    const int lane  = threadIdx.x & 63;
    if (token >= T_TOKENS) return;

    const float x = in[(size_t)token * N_EXP + lane];

    // argmax with first-index tiebreak (matches jnp.argmax)
    float v = x; int idx = lane;
    #pragma unroll
    for (int off = 32; off; off >>= 1) {
        float vo = __shfl_xor(v, off);
        int   io = __shfl_xor(idx, off);
        if (vo > v || (vo == v && io < idx)) { v = vo; idx = io; }
    }
    const float m  = v;
    const int   i1 = idx;

    // softmax denominator
    float s = expf(x - m);
    #pragma unroll
    for (int off = 32; off; off >>= 1) s += __shfl_xor(s, off);

    // second argmax (exclude i1)
    float v2 = (lane == i1) ? -INFINITY : x;
    int idx2 = lane;
    #pragma unroll
    for (int off = 32; off; off >>= 1) {
        float vo = __shfl_xor(v2, off);
        int   io = __shfl_xor(idx2, off);
        if (vo > v2 || (vo == v2 && io < idx2)) { v2 = vo; idx2 = io; }
    }

    if (lane == 0) {
        top1[token] = i1;
        top2[token] = idx2;
        w1[token]   = 1.0f / s;
        w2[token]   = expf(v2 - m) / s;
    }
}

// ---------------------------------------------------------------------------
// Kernel 2: one 1024-thread block per expert. Two-level parallel scan gives
// each matched token its cumsum rank; kept tokens scatter w / 1.0 directly
// into the (memset-zeroed) cb_weight / sec_mask tensors. Also writes
// used_capacity. Scatter touches <= 2 lines per token — negligible traffic.
// ---------------------------------------------------------------------------
__global__ __launch_bounds__(1024) void moe_rank_scatter_kernel(
    const int* __restrict__ top1, const int* __restrict__ top2,
    const float* __restrict__ w1, const float* __restrict__ w2,
    float* __restrict__ out)
{
    const int e    = blockIdx.x;
    const int tid  = threadIdx.x;
    const int lane = tid & 63;
    const int wid  = tid >> 6;           // 16 waves

    __shared__ int wsA[16], wsB[16];

    float* __restrict__ cb  = out + N_EXP;
    float* __restrict__ sec = cb + (size_t)T_TOKENS * ROWSZ;

    // ---------------- pass 1: top1 ----------------
    const int4 a1 = ((const int4*)top1)[tid * 2];
    const int4 b1 = ((const int4*)top1)[tid * 2 + 1];
    const int m0 = (a1.x == e), m1 = (a1.y == e), m2 = (a1.z == e), m3 = (a1.w == e);
    const int m4 = (b1.x == e), m5 = (b1.y == e), m6 = (b1.z == e), m7 = (b1.w == e);
    const int cnt1 = m0 + m1 + m2 + m3 + m4 + m5 + m6 + m7;

    int sc = cnt1;
    #pragma unroll
    for (int off = 1; off < 64; off <<= 1) {
        int n = __shfl_up(sc, off);
        if (lane >= off) sc += n;
    }
    if (lane == 63) wsA[wid] = sc;
    __syncthreads();
    int wbase = 0, total1 = 0;
    #pragma unroll
    for (int w = 0; w < 16; ++w) {
        const int sv = wsA[w];
        if (w < wid) wbase += sv;
        total1 += sv;
    }
    {
        int r = wbase + sc - cnt1;       // exclusive prefix for this segment
        const int t0 = tid * 8;
        #define SCAT1(K, MK)                                                  \
            if (MK) {                                                         \
                if (r < CAP) {                                                \
                    const size_t o = (size_t)(t0 + K) * ROWSZ + e * CAP + r;  \
                    cb[o]  = w1[t0 + K];                                      \
                    sec[o] = 1.0f;                                            \
                }                                                             \
                ++r;                                                          \
            }
        SCAT1(0, m0) SCAT1(1, m1) SCAT1(2, m2) SCAT1(3, m3)
        SCAT1(4, m4) SCAT1(5, m5) SCAT1(6, m6) SCAT1(7, m7)
        #undef SCAT1
    }

    // ---------------- pass 2: top2 (offset by total1) ----------------
    const int4 a2 = ((const int4*)top2)[tid * 2];
    const int4 b2 = ((const int4*)top2)[tid * 2 + 1];
    const int n0 = (a2.x == e), n1 = (a2.y == e), n2 = (a2.z == e), n3 = (a2.w == e);
    const int n4 = (b2.x == e), n5 = (b2.y == e), n6 = (b2.z == e), n7 = (b2.w == e);
    const int cnt2 = n0 + n1 + n2 + n3 + n4 + n5 + n6 + n7;

    int sc2 = cnt2;
    #pragma unroll
    for (int off = 1; off < 64; off <<= 1) {
        int n = __shfl_up(sc2, off);
        if (lane >= off) sc2 += n;
    }
    if (lane == 63) wsB[wid] = sc2;
    __syncthreads();
    int wbase2 = 0, total2 = 0;
    #pragma unroll
    for (int w = 0; w < 16; ++w) {
        const int sv = wsB[w];
        if (w < wid) wbase2 += sv;
        total2 += sv;
    }
    {
        int r = total1 + wbase2 + sc2 - cnt2;
        const int t0 = tid * 8;
        #define SCAT2(K, NK)                                                  \
            if (NK) {                                                         \
                if (r < CAP) {                                                \
                    const size_t o = (size_t)(t0 + K) * ROWSZ + e * CAP + r;  \
                    cb[o]  = w2[t0 + K];                                      \
                    sec[o] = 1.0f;                                            \
                }                                                             \
                ++r;                                                          \
            }
        SCAT2(0, n0) SCAT2(1, n1) SCAT2(2, n2) SCAT2(3, n3)
        SCAT2(4, n4) SCAT2(5, n5) SCAT2(6, n6) SCAT2(7, n7)
        #undef SCAT2
    }

    if (tid == 0) {
        const int kept1 = min(total1, CAP);
        const int kept2 = min(max(CAP - total1, 0), total2);
        out[e] = (float)(kept1 + kept2);
    }
}

// ---------------------------------------------------------------------------
extern "C" void kernel_launch(void* const* d_in, const int* in_sizes, int n_in,
                              void* d_out, int out_size, void* d_ws, size_t ws_size,
                              hipStream_t stream) {
    const float* in  = (const float*)d_in[0];
    float*       out = (float*)d_out;

    // workspace: top1 | top2 (int[T]) | w1 | w2 (float[T])
    int*   top1 = (int*)d_ws;
    int*   top2 = top1 + T_TOKENS;
    float* w1   = (float*)(top2 + T_TOKENS);
    float* w2   = w1 + T_TOKENS;

    // Bulk zeros via the tuned rocclr fill (measured 6.5 TB/s vs our
    // custom streamer's 5.6): zero everything, then scatter values on top.
    hipMemsetAsync(d_out, 0, (size_t)out_size * sizeof(float), stream);

    moe_topk_kernel<<<T_TOKENS / 4, 256, 0, stream>>>(in, top1, top2, w1, w2);
    moe_rank_scatter_kernel<<<N_EXP, 1024, 0, stream>>>(top1, top2, w1, w2, out);
}

// Round 7
// 231.398 us; speedup vs baseline: 1.2419x; 1.0043x over previous
//
#include <hip/hip_runtime.h>
#include <hip/hip_bf16.h>
#include <math.h>

#define T_TOKENS 8192
#define N_EXP    64
#define CAP      320   // floor(2 * 1.25 * 8192 / 64) = 320, even, > MIN_CAPACITY
#define ROWSZ    (N_EXP * CAP)       // 20480 floats per token row

// ---------------------------------------------------------------------------
// Kernel 1: per-token softmax + top-2. FOUR tokens per 64-lane wave:
// 16 lanes per token, each lane holds 4 experts (one float4 load).
// Butterfly offsets 8..1 stay within the 16-lane token group.
// ---------------------------------------------------------------------------
__global__ __launch_bounds__(256) void moe_topk_kernel(
    const float* __restrict__ in,
    int* __restrict__ top1, int* __restrict__ top2,
    float* __restrict__ w1, float* __restrict__ w2)
{
    const int lane = threadIdx.x & 63;
    const int wv   = threadIdx.x >> 6;          // 0..3 wave in block
    const int g    = lane >> 4;                 // 0..3 token within wave
    const int sub  = lane & 15;                 // 0..15 lane within token
    const int t    = blockIdx.x * 16 + wv * 4 + g;

    const float4 xv = ((const float4*)in)[(size_t)t * 16 + sub];
    const int b0 = sub * 4;

    // ---- argmax, first-index tiebreak (strict > keeps earliest) ----
    float v = xv.x; int idx = b0;
    if (xv.y > v) { v = xv.y; idx = b0 + 1; }
    if (xv.z > v) { v = xv.z; idx = b0 + 2; }
    if (xv.w > v) { v = xv.w; idx = b0 + 3; }
    #pragma unroll
    for (int off = 8; off; off >>= 1) {
        float vo = __shfl_xor(v, off);
        int   io = __shfl_xor(idx, off);
        if (vo > v || (vo == v && io < idx)) { v = vo; idx = io; }
    }
    const float m  = v;
    const int   i1 = idx;

    // ---- softmax denominator ----
    float s = expf(xv.x - m) + expf(xv.y - m) + expf(xv.z - m) + expf(xv.w - m);
    #pragma unroll
    for (int off = 8; off; off >>= 1) s += __shfl_xor(s, off);

    // ---- second argmax (exclude i1) ----
    const float c0 = (b0     == i1) ? -INFINITY : xv.x;
    const float c1 = (b0 + 1 == i1) ? -INFINITY : xv.y;
    const float c2 = (b0 + 2 == i1) ? -INFINITY : xv.z;
    const float c3 = (b0 + 3 == i1) ? -INFINITY : xv.w;
    float v2 = c0; int idx2 = b0;
    if (c1 > v2) { v2 = c1; idx2 = b0 + 1; }
    if (c2 > v2) { v2 = c2; idx2 = b0 + 2; }
    if (c3 > v2) { v2 = c3; idx2 = b0 + 3; }
    #pragma unroll
    for (int off = 8; off; off >>= 1) {
        float vo = __shfl_xor(v2, off);
        int   io = __shfl_xor(idx2, off);
        if (vo > v2 || (vo == v2 && io < idx2)) { v2 = vo; idx2 = io; }
    }

    if (sub == 0) {
        top1[t] = i1;
        top2[t] = idx2;
        w1[t]   = 1.0f / s;
        w2[t]   = expf(v2 - m) / s;
    }
}

// ---------------------------------------------------------------------------
// Kernel 2: one 1024-thread block per expert. Two-level parallel scan gives
// each matched token its cumsum rank; kept tokens scatter w / 1.0 directly
// into the (memset-zeroed) cb_weight / sec_mask tensors. Also writes
// used_capacity.
// ---------------------------------------------------------------------------
__global__ __launch_bounds__(1024) void moe_rank_scatter_kernel(
    const int* __restrict__ top1, const int* __restrict__ top2,
    const float* __restrict__ w1, const float* __restrict__ w2,
    float* __restrict__ out)
{
    const int e    = blockIdx.x;
    const int tid  = threadIdx.x;
    const int lane = tid & 63;
    const int wid  = tid >> 6;           // 16 waves

    __shared__ int wsA[16], wsB[16];

    float* __restrict__ cb  = out + N_EXP;
    float* __restrict__ sec = cb + (size_t)T_TOKENS * ROWSZ;

    // ---------------- pass 1: top1 ----------------
    const int4 a1 = ((const int4*)top1)[tid * 2];
    const int4 b1 = ((const int4*)top1)[tid * 2 + 1];
    const int m0 = (a1.x == e), m1 = (a1.y == e), m2 = (a1.z == e), m3 = (a1.w == e);
    const int m4 = (b1.x == e), m5 = (b1.y == e), m6 = (b1.z == e), m7 = (b1.w == e);
    const int cnt1 = m0 + m1 + m2 + m3 + m4 + m5 + m6 + m7;

    int sc = cnt1;
    #pragma unroll
    for (int off = 1; off < 64; off <<= 1) {
        int n = __shfl_up(sc, off);
        if (lane >= off) sc += n;
    }
    if (lane == 63) wsA[wid] = sc;
    __syncthreads();
    int wbase = 0, total1 = 0;
    #pragma unroll
    for (int w = 0; w < 16; ++w) {
        const int sv = wsA[w];
        if (w < wid) wbase += sv;
        total1 += sv;
    }
    {
        int r = wbase + sc - cnt1;       // exclusive prefix for this segment
        const int t0 = tid * 8;
        #define SCAT1(K, MK)                                                  \
            if (MK) {                                                         \
                if (r < CAP) {                                                \
                    const size_t o = (size_t)(t0 + K) * ROWSZ + e * CAP + r;  \
                    cb[o]  = w1[t0 + K];                                      \
                    sec[o] = 1.0f;                                            \
                }                                                             \
                ++r;                                                          \
            }
        SCAT1(0, m0) SCAT1(1, m1) SCAT1(2, m2) SCAT1(3, m3)
        SCAT1(4, m4) SCAT1(5, m5) SCAT1(6, m6) SCAT1(7, m7)
        #undef SCAT1
    }

    // ---------------- pass 2: top2 (offset by total1) ----------------
    const int4 a2 = ((const int4*)top2)[tid * 2];
    const int4 b2 = ((const int4*)top2)[tid * 2 + 1];
    const int n0 = (a2.x == e), n1 = (a2.y == e), n2 = (a2.z == e), n3 = (a2.w == e);
    const int n4 = (b2.x == e), n5 = (b2.y == e), n6 = (b2.z == e), n7 = (b2.w == e);
    const int cnt2 = n0 + n1 + n2 + n3 + n4 + n5 + n6 + n7;

    int sc2 = cnt2;
    #pragma unroll
    for (int off = 1; off < 64; off <<= 1) {
        int n = __shfl_up(sc2, off);
        if (lane >= off) sc2 += n;
    }
    if (lane == 63) wsB[wid] = sc2;
    __syncthreads();
    int wbase2 = 0, total2 = 0;
    #pragma unroll
    for (int w = 0; w < 16; ++w) {
        const int sv = wsB[w];
        if (w < wid) wbase2 += sv;
        total2 += sv;
    }
    {
        int r = total1 + wbase2 + sc2 - cnt2;
        const int t0 = tid * 8;
        #define SCAT2(K, NK)                                                  \
            if (NK) {                                                         \
                if (r < CAP) {                                                \
                    const size_t o = (size_t)(t0 + K) * ROWSZ + e * CAP + r;  \
                    cb[o]  = w2[t0 + K];                                      \
                    sec[o] = 1.0f;                                            \
                }                                                             \
                ++r;                                                          \
            }
        SCAT2(0, n0) SCAT2(1, n1) SCAT2(2, n2) SCAT2(3, n3)
        SCAT2(4, n4) SCAT2(5, n5) SCAT2(6, n6) SCAT2(7, n7)
        #undef SCAT2
    }

    if (tid == 0) {
        const int kept1 = min(total1, CAP);
        const int kept2 = min(max(CAP - total1, 0), total2);
        out[e] = (float)(kept1 + kept2);
    }
}

// ---------------------------------------------------------------------------
extern "C" void kernel_launch(void* const* d_in, const int* in_sizes, int n_in,
                              void* d_out, int out_size, void* d_ws, size_t ws_size,
                              hipStream_t stream) {
    const float* in  = (const float*)d_in[0];
    float*       out = (float*)d_out;

    // workspace: top1 | top2 (int[T]) | w1 | w2 (float[T])
    int*   top1 = (int*)d_ws;
    int*   top2 = top1 + T_TOKENS;
    float* w1   = (float*)(top2 + T_TOKENS);
    float* w2   = w1 + T_TOKENS;

    // Bulk zeros via the tuned rocclr fill (6.5+ TB/s); scatter values on top.
    hipMemsetAsync(d_out, 0, (size_t)out_size * sizeof(float), stream);

    moe_topk_kernel<<<T_TOKENS / 16, 256, 0, stream>>>(in, top1, top2, w1, w2);
    moe_rank_scatter_kernel<<<N_EXP, 1024, 0, stream>>>(top1, top2, w1, w2, out);
}